// Round 1
// baseline (314.781 us; speedup 1.0000x reference)
//
#include <hip/hip_runtime.h>
#include <hip/hip_bf16.h>
#include <stdint.h>

typedef short v8s __attribute__((ext_vector_type(8)));
typedef float v4f __attribute__((ext_vector_type(4)));
typedef unsigned short u16;

// ---------- helpers ----------
__device__ __forceinline__ u16 f2bf(float f) {
    unsigned u = __builtin_bit_cast(unsigned, f);
    u += 0x7FFFu + ((u >> 16) & 1u);   // RNE
    return (u16)(u >> 16);
}

__device__ __forceinline__ void gload_lds16(const void* g, const void* lds) {
    __builtin_amdgcn_global_load_lds(
        (const __attribute__((address_space(1))) unsigned int*)(unsigned long long)g,
        (__attribute__((address_space(3))) unsigned int*)(unsigned int)(unsigned long long)lds,
        16, 0, 0);
}

// ---------- fp32 -> bf16 conversion ----------
__global__ __launch_bounds__(256) void cvt_bf16(const float* __restrict__ in,
                                                u16* __restrict__ out, int n4) {
    int i = blockIdx.x * 256 + threadIdx.x;
    if (i < n4) {
        float4 v = ((const float4*)in)[i];
        ((ushort4*)out)[i] = make_ushort4(f2bf(v.x), f2bf(v.y), f2bf(v.z), f2bf(v.w));
    }
}

// ---------- QKV projection GEMM (m97 structure) ----------
// C[m][n] = sum_k X[m][k] * W[n][k] + bias[n]
// M=8192 (b*2048+s), N=1024 (h*64+dd), K=1024
// MODE 0: Q  -> [bh][s][d] bf16, scaled by 0.125
// MODE 1: K  -> [bh][s][d] bf16
// MODE 2: V  -> V^T [bh][d][s] bf16  (transposed via LDS)
template <int MODE>
__global__ __launch_bounds__(256, 2)
void qkv_gemm(const u16* __restrict__ X, const u16* __restrict__ W,
              const float* __restrict__ bias, u16* __restrict__ Out) {
    __shared__ __align__(16) char smem[34816];
    char* ldsA = smem;            // [128][64] bf16 = 16 KB
    char* ldsB = smem + 16384;    // [128][64] bf16 = 16 KB
    u16*  ldsE = (u16*)smem;      // epilogue [128][136]

    const int t = threadIdx.x;
    const int lane = t & 63, wave = t >> 6;
    const int lhi = lane >> 4, llo = lane & 15;
    const int wm = wave >> 1, wn = wave & 1;
    const int m0 = (blockIdx.x >> 3) * 128;
    const int n0 = (blockIdx.x & 7) * 128;

    v4f acc[4][4] = {};

    for (int k0 = 0; k0 < 1024; k0 += 64) {
        #pragma unroll
        for (int i = 0; i < 4; ++i) {
            int o = (i * 256 + t) * 16;            // byte offset in tile
            int row = o >> 7, c = (o >> 4) & 7;
            const char* wbaseA = ldsA + (i * 256 + wave * 64) * 16;
            const char* wbaseB = ldsB + (i * 256 + wave * 64) * 16;
            gload_lds16(X + (m0 + row) * 1024 + k0 + c * 8, wbaseA);
            gload_lds16(W + (n0 + row) * 1024 + k0 + c * 8, wbaseB);
        }
        __syncthreads();
        #pragma unroll
        for (int s = 0; s < 2; ++s) {
            v8s af[4], bf[4];
            #pragma unroll
            for (int i = 0; i < 4; ++i)
                af[i] = *(const v8s*)(ldsA + (wm * 64 + i * 16 + llo) * 128 + (lhi + 4 * s) * 16);
            #pragma unroll
            for (int j = 0; j < 4; ++j)
                bf[j] = *(const v8s*)(ldsB + (wn * 64 + j * 16 + llo) * 128 + (lhi + 4 * s) * 16);
            #pragma unroll
            for (int i = 0; i < 4; ++i)
                #pragma unroll
                for (int j = 0; j < 4; ++j)
                    acc[i][j] = __builtin_amdgcn_mfma_f32_16x16x32_bf16(af[i], bf[j], acc[i][j], 0, 0, 0);
        }
        __syncthreads();
    }

    // epilogue: bias (+scale) -> bf16 -> LDS -> coalesced global stores
    float bv_[4];
    #pragma unroll
    for (int j = 0; j < 4; ++j) bv_[j] = bias[n0 + wn * 64 + j * 16 + llo];

    #pragma unroll
    for (int i = 0; i < 4; ++i) {
        #pragma unroll
        for (int j = 0; j < 4; ++j) {
            #pragma unroll
            for (int r = 0; r < 4; ++r) {
                int ml = wm * 64 + i * 16 + lhi * 4 + r;
                int nl = wn * 64 + j * 16 + llo;
                float v = acc[i][j][r] + bv_[j];
                if (MODE == 0) v *= 0.125f;      // 1/sqrt(64), exact in bf16
                u16 hh = f2bf(v);
                if (MODE == 2) ldsE[nl * 136 + ml] = hh;
                else           ldsE[ml * 136 + nl] = hh;
            }
        }
    }
    __syncthreads();

    const int row = t >> 1, half = t & 1;
    if (MODE == 2) {
        int n = n0 + row, hh = n >> 6, dd = n & 63;
        int b = m0 >> 11, sbase = (m0 & 2047) + half * 64;
        u16* dst = Out + ((b * 16 + hh) * 64 + dd) * 2048 + sbase;
        #pragma unroll
        for (int j = 0; j < 8; ++j)
            *(v8s*)(dst + j * 8) = *(const v8s*)&ldsE[row * 136 + half * 64 + j * 8];
    } else {
        int m = m0 + row, b = m >> 11, s = m & 2047;
        int hh = (n0 + half * 64) >> 6;
        u16* dst = Out + ((b * 16 + hh) * 2048 + s) * 64;
        #pragma unroll
        for (int j = 0; j < 8; ++j)
            *(v8s*)(dst + j * 8) = *(const v8s*)&ldsE[row * 136 + half * 64 + j * 8];
    }
}

// ---------- causal flash attention ----------
// Q [bh][s][d], K [bh][s][d], VT [bh][d][s] (all bf16), out fp32 [b][s][H]
__global__ __launch_bounds__(256, 2)
void flash_attn(const u16* __restrict__ Qg, const u16* __restrict__ Kg,
                const u16* __restrict__ VTg, const float* __restrict__ am,
                float* __restrict__ out) {
    __shared__ __align__(16) char smem[24576];
    char* ldsK = smem;                                  // [64][64] bf16 swizzled
    char* ldsV = smem + 8192;                           // VT [64][64] bf16 swizzled
    char* ldsP = smem + 16384 + (threadIdx.x >> 6) * 2048;  // per-wave [16][64]

    const int t = threadIdx.x;
    const int lane = t & 63, wave = t >> 6;
    const int lhi = lane >> 4, llo = lane & 15;
    const int qi = blockIdx.x, bh = blockIdx.y;
    const int b = bh >> 4, h = bh & 15;
    const int q0 = qi * 64;
    const int qw = q0 + wave * 16;

    // Q fragments in registers (Q pre-scaled by 1/8 in the GEMM)
    v8s qf[2];
    #pragma unroll
    for (int s = 0; s < 2; ++s)
        qf[s] = *(const v8s*)(Qg + (bh * 2048 + qw + llo) * 64 + lhi * 8 + 32 * s);

    float rowpen[4];
    #pragma unroll
    for (int r = 0; r < 4; ++r) {
        int q = qw + lhi * 4 + r;
        rowpen[r] = am[b * 2048 + q];   // >=1.0 means fully padded row
    }

    float mrow[4], lrow[4];
    v4f o_acc[4] = {};
    #pragma unroll
    for (int r = 0; r < 4; ++r) { mrow[r] = -1e30f; lrow[r] = 0.f; }

    for (int kj = 0; kj <= qi; ++kj) {
        const int kv0 = kj * 64;
        // stage K tile and VT tile (XOR-swizzled via pre-swizzled global source)
        #pragma unroll
        for (int i = 0; i < 2; ++i) {
            int o = (i * 256 + t) * 16;
            int row = o >> 7, sc = (o >> 4) & 7;
            int c = sc ^ (row & 7);
            const char* wbK = ldsK + (i * 256 + wave * 64) * 16;
            const char* wbV = ldsV + (i * 256 + wave * 64) * 16;
            gload_lds16(Kg + (bh * 2048 + kv0 + row) * 64 + c * 8, wbK);
            gload_lds16(VTg + (bh * 64 + row) * 2048 + kv0 + c * 8, wbV);
        }
        __syncthreads();

        // scores: S[q][kv] = Q . K^T   (16x64 per wave)
        v4f sacc[4] = {};
        #pragma unroll
        for (int s = 0; s < 2; ++s) {
            #pragma unroll
            for (int tt = 0; tt < 4; ++tt) {
                int row = tt * 16 + llo;
                int c = lhi + 4 * s;
                v8s kb = *(const v8s*)(ldsK + row * 128 + ((c ^ (row & 7)) << 4));
                sacc[tt] = __builtin_amdgcn_mfma_f32_16x16x32_bf16(qf[s], kb, sacc[tt], 0, 0, 0);
            }
        }

        // causal mask on diagonal tile
        if (kj == qi) {
            #pragma unroll
            for (int tt = 0; tt < 4; ++tt)
                #pragma unroll
                for (int r = 0; r < 4; ++r) {
                    int kvg = kv0 + tt * 16 + llo;
                    int qg2 = qw + lhi * 4 + r;
                    if (kvg > qg2) sacc[tt][r] = -1e30f;
                }
        }
        // padded-row mask (replace, like reference where())
        #pragma unroll
        for (int r = 0; r < 4; ++r)
            if (rowpen[r] >= 1.0f) {
                #pragma unroll
                for (int tt = 0; tt < 4; ++tt) sacc[tt][r] = -1e30f;
            }

        // online softmax per q-row
        float scale_o[4];
        #pragma unroll
        for (int r = 0; r < 4; ++r) {
            float mx = fmaxf(fmaxf(sacc[0][r], sacc[1][r]), fmaxf(sacc[2][r], sacc[3][r]));
            #pragma unroll
            for (int off = 8; off >= 1; off >>= 1) mx = fmaxf(mx, __shfl_xor(mx, off));
            float mn = fmaxf(mrow[r], mx);
            float sc = __expf(mrow[r] - mn);
            float rs = 0.f;
            u16 ph[4];
            #pragma unroll
            for (int tt = 0; tt < 4; ++tt) {
                float p = __expf(sacc[tt][r] - mn);
                rs += p;
                ph[tt] = f2bf(p);
            }
            #pragma unroll
            for (int off = 8; off >= 1; off >>= 1) rs += __shfl_xor(rs, off);
            lrow[r] = lrow[r] * sc + rs;
            mrow[r] = mn;
            scale_o[r] = sc;
            // write P row to per-wave LDS (swizzled)
            int ql = lhi * 4 + r;
            #pragma unroll
            for (int tt = 0; tt < 4; ++tt) {
                int kv = tt * 16 + llo;
                int ch = kv >> 3;
                *(u16*)(ldsP + ql * 128 + ((ch ^ (ql & 7)) << 4) + (kv & 7) * 2) = ph[tt];
            }
        }
        // rescale O
        #pragma unroll
        for (int dt = 0; dt < 4; ++dt)
            #pragma unroll
            for (int r = 0; r < 4; ++r) o_acc[dt][r] *= scale_o[r];

        // PV: O += P @ V    (P from per-wave LDS, V^T rows from ldsV)
        #pragma unroll
        for (int s = 0; s < 2; ++s) {
            int c = lhi + 4 * s;
            int prow = llo;
            v8s pa = *(const v8s*)(ldsP + prow * 128 + ((c ^ (prow & 7)) << 4));
            #pragma unroll
            for (int dt = 0; dt < 4; ++dt) {
                int vrow = dt * 16 + llo;
                v8s vb = *(const v8s*)(ldsV + vrow * 128 + ((c ^ (vrow & 7)) << 4));
                o_acc[dt] = __builtin_amdgcn_mfma_f32_16x16x32_bf16(pa, vb, o_acc[dt], 0, 0, 0);
            }
        }
        __syncthreads();
    }

    // epilogue: out[b][q][h*64+d] = O/l
    #pragma unroll
    for (int r = 0; r < 4; ++r) {
        float inv = 1.0f / lrow[r];
        int q = qw + lhi * 4 + r;
        float* dst = out + (size_t)(b * 2048 + q) * 1024 + h * 64;
        #pragma unroll
        for (int dt = 0; dt < 4; ++dt)
            dst[dt * 16 + llo] = o_acc[dt][r] * inv;
    }
}

// ---------- launch ----------
extern "C" void kernel_launch(void* const* d_in, const int* in_sizes, int n_in,
                              void* d_out, int out_size, void* d_ws, size_t ws_size,
                              hipStream_t stream) {
    const float* x  = (const float*)d_in[0];
    const float* Wq = (const float*)d_in[1];
    const float* bq = (const float*)d_in[2];
    const float* Wk = (const float*)d_in[3];
    const float* bk = (const float*)d_in[4];
    const float* Wv = (const float*)d_in[5];
    const float* bv = (const float*)d_in[6];
    const float* amask = (const float*)d_in[7];
    float* out = (float*)d_out;

    char* ws = (char*)d_ws;
    u16* xb  = (u16*)(ws);                         // 16 MB
    u16* Wqb = (u16*)(ws + 16777216);              // 2 MB
    u16* Wkb = (u16*)(ws + 16777216 + 2097152);
    u16* Wvb = (u16*)(ws + 16777216 + 2 * 2097152);
    u16* Qg  = (u16*)(ws + 23068672);              // 16 MB
    u16* Kg  = (u16*)(ws + 39845888);              // 16 MB
    u16* VTg = (u16*)(ws + 56623104);              // 16 MB

    cvt_bf16<<<8192, 256, 0, stream>>>(x, xb, 2097152);
    cvt_bf16<<<1024, 256, 0, stream>>>(Wq, Wqb, 262144);
    cvt_bf16<<<1024, 256, 0, stream>>>(Wk, Wkb, 262144);
    cvt_bf16<<<1024, 256, 0, stream>>>(Wv, Wvb, 262144);

    qkv_gemm<0><<<512, 256, 0, stream>>>(xb, Wqb, bq, Qg);
    qkv_gemm<1><<<512, 256, 0, stream>>>(xb, Wkb, bk, Kg);
    qkv_gemm<2><<<512, 256, 0, stream>>>(xb, Wvb, bv, VTg);

    flash_attn<<<dim3(32, 64), 256, 0, stream>>>(Qg, Kg, VTg, amask, out);
}

// Round 2
// 178.898 us; speedup vs baseline: 1.7596x; 1.7596x over previous
//
#include <hip/hip_runtime.h>
#include <hip/hip_bf16.h>
#include <stdint.h>

typedef short v8s __attribute__((ext_vector_type(8)));
typedef float v4f __attribute__((ext_vector_type(4)));
typedef unsigned long long u64;
typedef unsigned short u16;
typedef unsigned int u32;
typedef u64 v2u __attribute__((ext_vector_type(2)));

// ---------- helpers ----------
__device__ __forceinline__ u16 f2bf(float f) {
    unsigned u = __builtin_bit_cast(unsigned, f);
    u += 0x7FFFu + ((u >> 16) & 1u);   // RNE
    return (u16)(u >> 16);
}

__device__ __forceinline__ u32 cvt_pk_bf16(float lo, float hi) {
    u32 r;
    asm("v_cvt_pk_bf16_f32 %0, %1, %2" : "=v"(r) : "v"(lo), "v"(hi));
    return r;
}

__device__ __forceinline__ float ex2(float x) {   // 2^x
    float r;
    asm("v_exp_f32 %0, %1" : "=v"(r) : "v"(x));
    return r;
}

__device__ __forceinline__ void gload_lds16(const void* g, const void* lds) {
    __builtin_amdgcn_global_load_lds(
        (const __attribute__((address_space(1))) unsigned int*)(unsigned long long)g,
        (__attribute__((address_space(3))) unsigned int*)(unsigned int)(unsigned long long)lds,
        16, 0, 0);
}

// ---------- fp32 -> bf16 conversion ----------
__global__ __launch_bounds__(256) void cvt_bf16(const float* __restrict__ in,
                                                u16* __restrict__ out, int n4) {
    int i = blockIdx.x * 256 + threadIdx.x;
    if (i < n4) {
        float4 v = ((const float4*)in)[i];
        ((ushort4*)out)[i] = make_ushort4(f2bf(v.x), f2bf(v.y), f2bf(v.z), f2bf(v.w));
    }
}

// ---------- QKV projection GEMM (m97 structure) ----------
// C[m][n] = sum_k X[m][k] * W[n][k] + bias[n]
// MODE 0: Q  -> [bh][s][d] bf16, scaled by 0.125*log2(e)  (base-2 softmax)
// MODE 1: K  -> [bh][s][d] bf16
// MODE 2: V  -> V^T [bh][d][s] bf16  (transposed via LDS)
template <int MODE>
__global__ __launch_bounds__(256, 2)
void qkv_gemm(const u16* __restrict__ X, const u16* __restrict__ W,
              const float* __restrict__ bias, u16* __restrict__ Out) {
    __shared__ __align__(16) char smem[34816];
    char* ldsA = smem;            // [128][64] bf16 = 16 KB
    char* ldsB = smem + 16384;    // [128][64] bf16 = 16 KB
    u16*  ldsE = (u16*)smem;      // epilogue [128][136]

    const int t = threadIdx.x;
    const int lane = t & 63, wave = t >> 6;
    const int lhi = lane >> 4, llo = lane & 15;
    const int wm = wave >> 1, wn = wave & 1;
    const int m0 = (blockIdx.x >> 3) * 128;
    const int n0 = (blockIdx.x & 7) * 128;

    v4f acc[4][4] = {};

    for (int k0 = 0; k0 < 1024; k0 += 64) {
        #pragma unroll
        for (int i = 0; i < 4; ++i) {
            int o = (i * 256 + t) * 16;            // byte offset in tile
            int row = o >> 7, c = (o >> 4) & 7;
            const char* wbaseA = ldsA + (i * 256 + wave * 64) * 16;
            const char* wbaseB = ldsB + (i * 256 + wave * 64) * 16;
            gload_lds16(X + (m0 + row) * 1024 + k0 + c * 8, wbaseA);
            gload_lds16(W + (n0 + row) * 1024 + k0 + c * 8, wbaseB);
        }
        __syncthreads();
        #pragma unroll
        for (int s = 0; s < 2; ++s) {
            v8s af[4], bf[4];
            #pragma unroll
            for (int i = 0; i < 4; ++i)
                af[i] = *(const v8s*)(ldsA + (wm * 64 + i * 16 + llo) * 128 + (lhi + 4 * s) * 16);
            #pragma unroll
            for (int j = 0; j < 4; ++j)
                bf[j] = *(const v8s*)(ldsB + (wn * 64 + j * 16 + llo) * 128 + (lhi + 4 * s) * 16);
            #pragma unroll
            for (int i = 0; i < 4; ++i)
                #pragma unroll
                for (int j = 0; j < 4; ++j)
                    acc[i][j] = __builtin_amdgcn_mfma_f32_16x16x32_bf16(af[i], bf[j], acc[i][j], 0, 0, 0);
        }
        __syncthreads();
    }

    // epilogue: bias (+scale) -> bf16 -> LDS -> coalesced global stores
    float bv_[4];
    #pragma unroll
    for (int j = 0; j < 4; ++j) bv_[j] = bias[n0 + wn * 64 + j * 16 + llo];

    #pragma unroll
    for (int i = 0; i < 4; ++i) {
        #pragma unroll
        for (int j = 0; j < 4; ++j) {
            #pragma unroll
            for (int r = 0; r < 4; ++r) {
                int ml = wm * 64 + i * 16 + lhi * 4 + r;
                int nl = wn * 64 + j * 16 + llo;
                float v = acc[i][j][r] + bv_[j];
                if (MODE == 0) v *= 0.18033688011112042f;   // 0.125 * log2(e)
                u16 hh = f2bf(v);
                if (MODE == 2) ldsE[nl * 136 + ml] = hh;
                else           ldsE[ml * 136 + nl] = hh;
            }
        }
    }
    __syncthreads();

    const int row = t >> 1, half = t & 1;
    if (MODE == 2) {
        int n = n0 + row, hh = n >> 6, dd = n & 63;
        int b = m0 >> 11, sbase = (m0 & 2047) + half * 64;
        u16* dst = Out + ((b * 16 + hh) * 64 + dd) * 2048 + sbase;
        #pragma unroll
        for (int j = 0; j < 8; ++j)
            *(v8s*)(dst + j * 8) = *(const v8s*)&ldsE[row * 136 + half * 64 + j * 8];
    } else {
        int m = m0 + row, b = m >> 11, s = m & 2047;
        int hh = (n0 + half * 64) >> 6;
        u16* dst = Out + ((b * 16 + hh) * 2048 + s) * 64;
        #pragma unroll
        for (int j = 0; j < 8; ++j)
            *(v8s*)(dst + j * 8) = *(const v8s*)&ldsE[row * 136 + half * 64 + j * 8];
    }
}

// ---------- causal flash attention (swapped QK^T, in-register softmax) ----------
// Q [bh][s][d] (pre-scaled by 0.125*log2e), K [bh][s][d], VT [bh][d][s] bf16
// out fp32 [b][s][H]
__global__ __launch_bounds__(256, 4)
void flash_attn(const u16* __restrict__ Qg, const u16* __restrict__ Kg,
                const u16* __restrict__ VTg, const float* __restrict__ am,
                float* __restrict__ out) {
    __shared__ __align__(16) char smem[25088];
    char* ldsK = smem;                                   // [64][64] bf16 swizzled
    char* ldsV = smem + 8192;                            // VT [64][64] bf16 swizzled
    char* ldsP = smem + 16384 + (threadIdx.x >> 6) * 2176;  // per-wave P [16 q][68 kv] u16 (136B rows)

    const int t = threadIdx.x;
    const int lane = t & 63, wave = t >> 6;
    const int lhi = lane >> 4, llo = lane & 15;
    const int bh = blockIdx.x;
    const int qi = 31 - blockIdx.y;        // heavy tiles dispatch first (LPT)
    const int b = bh >> 4, h = bh & 15;
    const int q0 = qi * 64;
    const int qw = q0 + wave * 16;
    const int q = qw + llo;                // this lane's q row

    // Q fragment (B-operand layout: row n=llo, k = lhi*8 + 32s)
    v8s qf[2];
    #pragma unroll
    for (int s = 0; s < 2; ++s)
        qf[s] = *(const v8s*)(Qg + (bh * 2048 + q) * 64 + lhi * 8 + 32 * s);

    const float rowpen = am[b * 2048 + q];   // >=1.0 means fully padded row

    float mrow = -1e30f, lrow = 0.f;
    v4f o_acc[4] = {};   // O^T: d = dt*16 + lhi*4 + r, col q = llo

    for (int kj = 0; kj <= qi; ++kj) {
        const int kv0 = kj * 64;
        // stage K tile and VT tile (XOR-swizzled via pre-swizzled global source)
        #pragma unroll
        for (int i = 0; i < 2; ++i) {
            int o = (i * 256 + t) * 16;
            int row = o >> 7, sc = (o >> 4) & 7;
            int c = sc ^ (row & 7);
            const char* wbK = ldsK + (i * 256 + wave * 64) * 16;
            const char* wbV = ldsV + (i * 256 + wave * 64) * 16;
            gload_lds16(Kg + (bh * 2048 + kv0 + row) * 64 + c * 8, wbK);
            gload_lds16(VTg + (bh * 64 + row) * 2048 + kv0 + c * 8, wbV);
        }
        __syncthreads();

        // S^T[kv][q] = K . Q^T : A = K rows (kv), B = Q rows (q)
        const int nt4 = (kj == qi) ? (wave + 1) : 4;   // skip fully-masked diag subtiles
        v4f sacc[4] = {};
        #pragma unroll
        for (int tt = 0; tt < 4; ++tt) {
            if (tt < nt4) {
                #pragma unroll
                for (int s = 0; s < 2; ++s) {
                    int row = tt * 16 + llo;
                    int c = lhi + 4 * s;
                    v8s kb = *(const v8s*)(ldsK + row * 128 + ((c ^ (row & 7)) << 4));
                    sacc[tt] = __builtin_amdgcn_mfma_f32_16x16x32_bf16(kb, qf[s], sacc[tt], 0, 0, 0);
                }
            }
        }

        // causal mask on diagonal tile (covers skipped subtiles too: sacc=0 -> -1e30)
        if (kj == qi) {
            #pragma unroll
            for (int tt = 0; tt < 4; ++tt)
                #pragma unroll
                for (int r = 0; r < 4; ++r) {
                    int kvg = kv0 + tt * 16 + lhi * 4 + r;
                    if (kvg > q) sacc[tt][r] = -1e30f;
                }
        }
        if (rowpen >= 1.0f) {
            #pragma unroll
            for (int tt = 0; tt < 4; ++tt)
                #pragma unroll
                for (int r = 0; r < 4; ++r) sacc[tt][r] = -1e30f;
        }

        // in-register online softmax (scores are base-2)
        float mx = fmaxf(fmaxf(sacc[0][0], sacc[0][1]), fmaxf(sacc[0][2], sacc[0][3]));
        #pragma unroll
        for (int tt = 1; tt < 4; ++tt) {
            float m2 = fmaxf(fmaxf(sacc[tt][0], sacc[tt][1]), fmaxf(sacc[tt][2], sacc[tt][3]));
            mx = fmaxf(mx, m2);
        }
        mx = fmaxf(mx, __shfl_xor(mx, 16));
        mx = fmaxf(mx, __shfl_xor(mx, 32));
        const float mn = fmaxf(mrow, mx);
        const float sc_o = ex2(mrow - mn);
        mrow = mn;

        float rs = 0.f;
        #pragma unroll
        for (int tt = 0; tt < 4; ++tt) {
            float p0 = ex2(sacc[tt][0] - mn);
            float p1 = ex2(sacc[tt][1] - mn);
            float p2 = ex2(sacc[tt][2] - mn);
            float p3 = ex2(sacc[tt][3] - mn);
            rs += (p0 + p1) + (p2 + p3);
            u32 w0 = cvt_pk_bf16(p0, p1);
            u32 w1 = cvt_pk_bf16(p2, p3);
            // P[q=llo][kv = tt*16 + lhi*4 + 0..3]
            *(u64*)(ldsP + llo * 136 + tt * 32 + lhi * 8) = (u64)w0 | ((u64)w1 << 32);
        }
        rs += __shfl_xor(rs, 16);
        rs += __shfl_xor(rs, 32);
        lrow = lrow * sc_o + rs;

        // rescale O (single scalar per lane)
        #pragma unroll
        for (int dt = 0; dt < 4; ++dt)
            #pragma unroll
            for (int r = 0; r < 4; ++r) o_acc[dt][r] *= sc_o;

        // PV: O^T[d][q] += V^T[d][kv] * P^T[kv][q] ; A = V^T rows (d), B = P rows (q)
        #pragma unroll
        for (int s = 0; s < 2; ++s) {
            u64 plo = *(const u64*)(ldsP + llo * 136 + lhi * 16 + s * 64);
            u64 phi = *(const u64*)(ldsP + llo * 136 + lhi * 16 + s * 64 + 8);
            v2u tmp; tmp.x = plo; tmp.y = phi;
            v8s pb = __builtin_bit_cast(v8s, tmp);
            #pragma unroll
            for (int dt = 0; dt < 4; ++dt) {
                int vrow = dt * 16 + llo;
                v8s vb = *(const v8s*)(ldsV + vrow * 128 + (((lhi + 4 * s) ^ (vrow & 7)) << 4));
                o_acc[dt] = __builtin_amdgcn_mfma_f32_16x16x32_bf16(vb, pb, o_acc[dt], 0, 0, 0);
            }
        }
        __syncthreads();
    }

    // epilogue: out[b][q][h*64 + d], d = dt*16 + lhi*4 + r -> float4 stores
    const float inv = 1.0f / lrow;
    float* dst = out + (size_t)(b * 2048 + q) * 1024 + h * 64 + lhi * 4;
    #pragma unroll
    for (int dt = 0; dt < 4; ++dt) {
        float4 o;
        o.x = o_acc[dt][0] * inv;
        o.y = o_acc[dt][1] * inv;
        o.z = o_acc[dt][2] * inv;
        o.w = o_acc[dt][3] * inv;
        *(float4*)(dst + dt * 16) = o;
    }
}

// ---------- launch ----------
extern "C" void kernel_launch(void* const* d_in, const int* in_sizes, int n_in,
                              void* d_out, int out_size, void* d_ws, size_t ws_size,
                              hipStream_t stream) {
    const float* x  = (const float*)d_in[0];
    const float* Wq = (const float*)d_in[1];
    const float* bq = (const float*)d_in[2];
    const float* Wk = (const float*)d_in[3];
    const float* bk = (const float*)d_in[4];
    const float* Wv = (const float*)d_in[5];
    const float* bv = (const float*)d_in[6];
    const float* amask = (const float*)d_in[7];
    float* out = (float*)d_out;

    char* ws = (char*)d_ws;
    u16* xb  = (u16*)(ws);                         // 16 MB
    u16* Wqb = (u16*)(ws + 16777216);              // 2 MB
    u16* Wkb = (u16*)(ws + 16777216 + 2097152);
    u16* Wvb = (u16*)(ws + 16777216 + 2 * 2097152);
    u16* Qg  = (u16*)(ws + 23068672);              // 16 MB
    u16* Kg  = (u16*)(ws + 39845888);              // 16 MB
    u16* VTg = (u16*)(ws + 56623104);              // 16 MB

    cvt_bf16<<<8192, 256, 0, stream>>>(x, xb, 2097152);
    cvt_bf16<<<1024, 256, 0, stream>>>(Wq, Wqb, 262144);
    cvt_bf16<<<1024, 256, 0, stream>>>(Wk, Wkb, 262144);
    cvt_bf16<<<1024, 256, 0, stream>>>(Wv, Wvb, 262144);

    qkv_gemm<0><<<512, 256, 0, stream>>>(xb, Wqb, bq, Qg);
    qkv_gemm<1><<<512, 256, 0, stream>>>(xb, Wkb, bk, Kg);
    qkv_gemm<2><<<512, 256, 0, stream>>>(xb, Wvb, bv, VTg);

    flash_attn<<<dim3(64, 32), 256, 0, stream>>>(Qg, Kg, VTg, amask, out);
}

// Round 3
// 164.458 us; speedup vs baseline: 1.9140x; 1.0878x over previous
//
#include <hip/hip_runtime.h>
#include <hip/hip_bf16.h>
#include <stdint.h>

typedef short v8s __attribute__((ext_vector_type(8)));
typedef float v4f __attribute__((ext_vector_type(4)));
typedef unsigned long long u64;
typedef unsigned short u16;
typedef unsigned int u32;
typedef u64 v2u __attribute__((ext_vector_type(2)));

// ---------- helpers ----------
__device__ __forceinline__ u16 f2bf(float f) {
    unsigned u = __builtin_bit_cast(unsigned, f);
    u += 0x7FFFu + ((u >> 16) & 1u);   // RNE
    return (u16)(u >> 16);
}

__device__ __forceinline__ u32 cvt_pk_bf16(float lo, float hi) {
    u32 r;
    asm("v_cvt_pk_bf16_f32 %0, %1, %2" : "=v"(r) : "v"(lo), "v"(hi));
    return r;
}

__device__ __forceinline__ float ex2(float x) {   // 2^x
    float r;
    asm("v_exp_f32 %0, %1" : "=v"(r) : "v"(x));
    return r;
}

__device__ __forceinline__ void gload_lds16(const void* g, const void* lds) {
    __builtin_amdgcn_global_load_lds(
        (const __attribute__((address_space(1))) unsigned int*)(unsigned long long)g,
        (__attribute__((address_space(3))) unsigned int*)(unsigned int)(unsigned long long)lds,
        16, 0, 0);
}

// ---------- fused fp32 -> bf16 conversion (x, Wq, Wk, Wv in one launch) ----------
__global__ __launch_bounds__(256) void cvt_all(const float* __restrict__ x,
                                               const float* __restrict__ wq,
                                               const float* __restrict__ wk,
                                               const float* __restrict__ wv,
                                               u16* __restrict__ xb, u16* __restrict__ wqb,
                                               u16* __restrict__ wkb, u16* __restrict__ wvb) {
    int i = blockIdx.x * 256 + threadIdx.x;   // v4 index over concatenated regions
    const float* in;
    u16* out;
    if (i < 2097152)      { in = x;  out = xb; }
    else if (i < 2359296) { in = wq; out = wqb; i -= 2097152; }
    else if (i < 2621440) { in = wk; out = wkb; i -= 2359296; }
    else                  { in = wv; out = wvb; i -= 2621440; }
    float4 v = ((const float4*)in)[i];
    ((ushort4*)out)[i] = make_ushort4(f2bf(v.x), f2bf(v.y), f2bf(v.z), f2bf(v.w));
}

// ---------- merged QKV projection GEMM (m97 structure, 3 modes in one launch) ----------
// C[m][n] = sum_k X[m][k] * W[n][k] + bias[n]
// mode 0: Q -> [bh][s][d] bf16, scaled by 0.125*log2(e)
// mode 1: K -> [bh][s][d] bf16
// mode 2: V -> V^T [bh][d][s] bf16 (transposed via LDS)
__global__ __launch_bounds__(256, 2)
void qkv_gemm_all(const u16* __restrict__ X,
                  const u16* __restrict__ Wq, const u16* __restrict__ Wk, const u16* __restrict__ Wv,
                  const float* __restrict__ bq, const float* __restrict__ bk, const float* __restrict__ bv,
                  u16* __restrict__ Qg, u16* __restrict__ Kg, u16* __restrict__ VTg) {
    __shared__ __align__(16) char smem[34816];
    char* ldsA = smem;            // [128][64] bf16 = 16 KB
    char* ldsB = smem + 16384;    // [128][64] bf16 = 16 KB
    u16*  ldsE = (u16*)smem;      // epilogue [128][136]

    const int mode = blockIdx.x >> 9;
    const int bx = blockIdx.x & 511;
    const u16* W = (mode == 0) ? Wq : (mode == 1) ? Wk : Wv;
    const float* bias = (mode == 0) ? bq : (mode == 1) ? bk : bv;
    u16* Out = (mode == 0) ? Qg : (mode == 1) ? Kg : VTg;

    const int t = threadIdx.x;
    const int lane = t & 63, wave = t >> 6;
    const int lhi = lane >> 4, llo = lane & 15;
    const int wm = wave >> 1, wn = wave & 1;
    const int m0 = (bx >> 3) * 128;
    const int n0 = (bx & 7) * 128;

    v4f acc[4][4] = {};

    for (int k0 = 0; k0 < 1024; k0 += 64) {
        #pragma unroll
        for (int i = 0; i < 4; ++i) {
            int o = (i * 256 + t) * 16;            // byte offset in tile
            int row = o >> 7, c = (o >> 4) & 7;
            const char* wbaseA = ldsA + (i * 256 + wave * 64) * 16;
            const char* wbaseB = ldsB + (i * 256 + wave * 64) * 16;
            gload_lds16(X + (m0 + row) * 1024 + k0 + c * 8, wbaseA);
            gload_lds16(W + (n0 + row) * 1024 + k0 + c * 8, wbaseB);
        }
        __syncthreads();
        __builtin_amdgcn_s_setprio(1);
        #pragma unroll
        for (int s = 0; s < 2; ++s) {
            v8s af[4], bf[4];
            #pragma unroll
            for (int i = 0; i < 4; ++i)
                af[i] = *(const v8s*)(ldsA + (wm * 64 + i * 16 + llo) * 128 + (lhi + 4 * s) * 16);
            #pragma unroll
            for (int j = 0; j < 4; ++j)
                bf[j] = *(const v8s*)(ldsB + (wn * 64 + j * 16 + llo) * 128 + (lhi + 4 * s) * 16);
            #pragma unroll
            for (int i = 0; i < 4; ++i)
                #pragma unroll
                for (int j = 0; j < 4; ++j)
                    acc[i][j] = __builtin_amdgcn_mfma_f32_16x16x32_bf16(af[i], bf[j], acc[i][j], 0, 0, 0);
        }
        __builtin_amdgcn_s_setprio(0);
        __syncthreads();
    }

    // epilogue: bias (+scale) -> bf16 -> LDS -> coalesced global stores
    float bv_[4];
    #pragma unroll
    for (int j = 0; j < 4; ++j) bv_[j] = bias[n0 + wn * 64 + j * 16 + llo];
    const float scl = (mode == 0) ? 0.18033688011112042f : 1.0f;   // 0.125 * log2(e)

    #pragma unroll
    for (int i = 0; i < 4; ++i) {
        #pragma unroll
        for (int j = 0; j < 4; ++j) {
            #pragma unroll
            for (int r = 0; r < 4; ++r) {
                int ml = wm * 64 + i * 16 + lhi * 4 + r;
                int nl = wn * 64 + j * 16 + llo;
                float v = (acc[i][j][r] + bv_[j]) * scl;
                u16 hh = f2bf(v);
                if (mode == 2) ldsE[nl * 136 + ml] = hh;
                else           ldsE[ml * 136 + nl] = hh;
            }
        }
    }
    __syncthreads();

    const int row = t >> 1, half = t & 1;
    if (mode == 2) {
        int n = n0 + row, hh = n >> 6, dd = n & 63;
        int b = m0 >> 11, sbase = (m0 & 2047) + half * 64;
        u16* dst = Out + ((b * 16 + hh) * 64 + dd) * 2048 + sbase;
        #pragma unroll
        for (int j = 0; j < 8; ++j)
            *(v8s*)(dst + j * 8) = *(const v8s*)&ldsE[row * 136 + half * 64 + j * 8];
    } else {
        int m = m0 + row, b = m >> 11, s = m & 2047;
        int hh = (n0 + half * 64) >> 6;
        u16* dst = Out + ((b * 16 + hh) * 2048 + s) * 64;
        #pragma unroll
        for (int j = 0; j < 8; ++j)
            *(v8s*)(dst + j * 8) = *(const v8s*)&ldsE[row * 136 + half * 64 + j * 8];
    }
}

// ---------- causal flash attention ----------
// swapped QK^T + in-register softmax + double-buffered K/V + defer-max
// Q [bh][s][d] (pre-scaled by 0.125*log2e), K [bh][s][d], VT [bh][d][s] bf16
// out fp32 [b][s][H]
__global__ __launch_bounds__(256, 3)
void flash_attn(const u16* __restrict__ Qg, const u16* __restrict__ Kg,
                const u16* __restrict__ VTg, const float* __restrict__ am,
                float* __restrict__ out) {
    __shared__ __align__(16) char smem[41472];
    char* ldsK = smem;                                   // 2 x [64][64] bf16 swizzled
    char* ldsV = smem + 16384;                           // 2 x VT [64][64] bf16 swizzled
    char* ldsP = smem + 32768 + (threadIdx.x >> 6) * 2176;  // per-wave P [16 q][68 kv] u16

    const int t = threadIdx.x;
    const int lane = t & 63, wave = t >> 6;
    const int lhi = lane >> 4, llo = lane & 15;
    const int bh = blockIdx.x;
    const int qi = 31 - blockIdx.y;        // heavy tiles dispatch first (LPT)
    const int b = bh >> 4, h = bh & 15;
    const int qw = qi * 64 + wave * 16;
    const int q = qw + llo;                // this lane's q row

    // Q fragment (B-operand layout: row n=llo, k = lhi*8 + 32s)
    v8s qf[2];
    #pragma unroll
    for (int s = 0; s < 2; ++s)
        qf[s] = *(const v8s*)(Qg + (bh * 2048 + q) * 64 + lhi * 8 + 32 * s);

    const float rowpen = am[b * 2048 + q];   // >=1.0 means fully padded row

    // stage K tile and VT tile (XOR-swizzled via pre-swizzled global source)
    const int srow = (t * 16) >> 7, ssc = ((t * 16) >> 4) & 7;
    const int sc1 = ssc ^ (srow & 7), sc2 = ssc ^ ((srow + 32) & 7);
    #define STAGE(buf, kj2) do {                                                   \
        const int kv0_ = (kj2) * 64;                                               \
        const char* wbK = ldsK + (buf) * 8192 + (wave * 64) * 16;                  \
        const char* wbV = ldsV + (buf) * 8192 + (wave * 64) * 16;                  \
        gload_lds16(Kg + (bh * 2048 + kv0_ + srow) * 64 + sc1 * 8, wbK);           \
        gload_lds16(VTg + (bh * 64 + srow) * 2048 + kv0_ + sc1 * 8, wbV);          \
        gload_lds16(Kg + (bh * 2048 + kv0_ + srow + 32) * 64 + sc2 * 8, wbK + 4096); \
        gload_lds16(VTg + (bh * 64 + srow + 32) * 2048 + kv0_ + sc2 * 8, wbV + 4096); \
    } while (0)

    float mrow = -1e30f, lrow = 0.f;
    v4f o_acc[4] = {};   // O^T: d = dt*16 + lhi*4 + r, col q = llo

    STAGE(0, 0);
    __syncthreads();

    for (int kj = 0; kj <= qi; ++kj) {
        const int cur = kj & 1;
        if (kj < qi) STAGE(cur ^ 1, kj + 1);   // prefetch: in flight during compute
        const char* K = ldsK + cur * 8192;
        const char* V = ldsV + cur * 8192;
        const int kv0 = kj * 64;

        // S^T[kv][q] = K . Q^T : A = K rows (kv), B = Q rows (q)
        const int nt4 = (kj == qi) ? (wave + 1) : 4;   // skip fully-masked diag subtiles
        v4f sacc[4] = {};
        __builtin_amdgcn_s_setprio(1);
        #pragma unroll
        for (int tt = 0; tt < 4; ++tt) {
            if (tt < nt4) {
                #pragma unroll
                for (int s = 0; s < 2; ++s) {
                    int row = tt * 16 + llo;
                    int c = lhi + 4 * s;
                    v8s kb = *(const v8s*)(K + row * 128 + ((c ^ (row & 7)) << 4));
                    sacc[tt] = __builtin_amdgcn_mfma_f32_16x16x32_bf16(kb, qf[s], sacc[tt], 0, 0, 0);
                }
            }
        }
        __builtin_amdgcn_s_setprio(0);

        // causal mask on diagonal tile (covers skipped subtiles too: sacc=0 -> -1e30)
        if (kj == qi) {
            #pragma unroll
            for (int tt = 0; tt < 4; ++tt)
                #pragma unroll
                for (int r = 0; r < 4; ++r) {
                    int kvg = kv0 + tt * 16 + lhi * 4 + r;
                    if (kvg > q) sacc[tt][r] = -1e30f;
                }
        }
        if (rowpen >= 1.0f) {
            #pragma unroll
            for (int tt = 0; tt < 4; ++tt)
                #pragma unroll
                for (int r = 0; r < 4; ++r) sacc[tt][r] = -1e30f;
        }

        // in-register online softmax (scores are base-2); defer-max rescale
        float mx = fmaxf(fmaxf(sacc[0][0], sacc[0][1]), fmaxf(sacc[0][2], sacc[0][3]));
        #pragma unroll
        for (int tt = 1; tt < 4; ++tt)
            mx = fmaxf(mx, fmaxf(fmaxf(sacc[tt][0], sacc[tt][1]), fmaxf(sacc[tt][2], sacc[tt][3])));
        mx = fmaxf(mx, __shfl_xor(mx, 16));
        mx = fmaxf(mx, __shfl_xor(mx, 32));

        if (__any(mx > mrow + 8.0f)) {        // rescale only on significant max growth
            const float mn = fmaxf(mrow, mx);
            const float sc_o = ex2(mrow - mn);
            mrow = mn;
            lrow *= sc_o;
            #pragma unroll
            for (int dt = 0; dt < 4; ++dt)
                #pragma unroll
                for (int r = 0; r < 4; ++r) o_acc[dt][r] *= sc_o;
        }

        float rs = 0.f;
        #pragma unroll
        for (int tt = 0; tt < 4; ++tt) {
            float p0 = ex2(sacc[tt][0] - mrow);
            float p1 = ex2(sacc[tt][1] - mrow);
            float p2 = ex2(sacc[tt][2] - mrow);
            float p3 = ex2(sacc[tt][3] - mrow);
            rs += (p0 + p1) + (p2 + p3);
            u32 w0 = cvt_pk_bf16(p0, p1);
            u32 w1 = cvt_pk_bf16(p2, p3);
            // P[q=llo][kv = tt*16 + lhi*4 + 0..3]
            *(u64*)(ldsP + llo * 136 + tt * 32 + lhi * 8) = (u64)w0 | ((u64)w1 << 32);
        }
        rs += __shfl_xor(rs, 16);
        rs += __shfl_xor(rs, 32);
        lrow += rs;

        // PV: O^T[d][q] += V^T[d][kv] * P^T[kv][q] ; A = V^T rows (d), B = P rows (q)
        __builtin_amdgcn_s_setprio(1);
        #pragma unroll
        for (int s = 0; s < 2; ++s) {
            u64 plo = *(const u64*)(ldsP + llo * 136 + lhi * 16 + s * 64);
            u64 phi = *(const u64*)(ldsP + llo * 136 + lhi * 16 + s * 64 + 8);
            v2u tmp; tmp.x = plo; tmp.y = phi;
            v8s pb = __builtin_bit_cast(v8s, tmp);
            #pragma unroll
            for (int dt = 0; dt < 4; ++dt) {
                int vrow = dt * 16 + llo;
                v8s vb = *(const v8s*)(V + vrow * 128 + (((lhi + 4 * s) ^ (vrow & 7)) << 4));
                o_acc[dt] = __builtin_amdgcn_mfma_f32_16x16x32_bf16(vb, pb, o_acc[dt], 0, 0, 0);
            }
        }
        __builtin_amdgcn_s_setprio(0);
        __syncthreads();   // buf[cur] reads done; prefetch into buf[cur^1] drained
    }

    // epilogue: out[b][q][h*64 + d], d = dt*16 + lhi*4 + r -> float4 stores
    const float inv = 1.0f / lrow;
    float* dst = out + (size_t)(b * 2048 + q) * 1024 + h * 64 + lhi * 4;
    #pragma unroll
    for (int dt = 0; dt < 4; ++dt) {
        float4 o;
        o.x = o_acc[dt][0] * inv;
        o.y = o_acc[dt][1] * inv;
        o.z = o_acc[dt][2] * inv;
        o.w = o_acc[dt][3] * inv;
        *(float4*)(dst + dt * 16) = o;
    }
}

// ---------- launch ----------
extern "C" void kernel_launch(void* const* d_in, const int* in_sizes, int n_in,
                              void* d_out, int out_size, void* d_ws, size_t ws_size,
                              hipStream_t stream) {
    const float* x  = (const float*)d_in[0];
    const float* Wq = (const float*)d_in[1];
    const float* bq = (const float*)d_in[2];
    const float* Wk = (const float*)d_in[3];
    const float* bk = (const float*)d_in[4];
    const float* Wv = (const float*)d_in[5];
    const float* bv = (const float*)d_in[6];
    const float* amask = (const float*)d_in[7];
    float* out = (float*)d_out;

    char* ws = (char*)d_ws;
    u16* xb  = (u16*)(ws);                         // 16 MB
    u16* Wqb = (u16*)(ws + 16777216);              // 2 MB
    u16* Wkb = (u16*)(ws + 16777216 + 2097152);
    u16* Wvb = (u16*)(ws + 16777216 + 2 * 2097152);
    u16* Qg  = (u16*)(ws + 23068672);              // 16 MB
    u16* Kg  = (u16*)(ws + 39845888);              // 16 MB
    u16* VTg = (u16*)(ws + 56623104);              // 16 MB

    cvt_all<<<11264, 256, 0, stream>>>(x, Wq, Wk, Wv, xb, Wqb, Wkb, Wvb);
    qkv_gemm_all<<<1536, 256, 0, stream>>>(xb, Wqb, Wkb, Wvb, bq, bk, bv, Qg, Kg, VTg);
    flash_attn<<<dim3(64, 32), 256, 0, stream>>>(Qg, Kg, VTg, amask, out);
}

// Round 4
// 159.791 us; speedup vs baseline: 1.9700x; 1.0292x over previous
//
#include <hip/hip_runtime.h>
#include <hip/hip_bf16.h>
#include <stdint.h>

typedef short v8s __attribute__((ext_vector_type(8)));
typedef float v4f __attribute__((ext_vector_type(4)));
typedef unsigned long long u64;
typedef unsigned short u16;
typedef unsigned int u32;
typedef u64 v2u __attribute__((ext_vector_type(2)));

// ---------- helpers ----------
__device__ __forceinline__ u16 f2bf(float f) {
    unsigned u = __builtin_bit_cast(unsigned, f);
    u += 0x7FFFu + ((u >> 16) & 1u);   // RNE
    return (u16)(u >> 16);
}

__device__ __forceinline__ u32 cvt_pk_bf16(float lo, float hi) {
    u32 r;
    asm("v_cvt_pk_bf16_f32 %0, %1, %2" : "=v"(r) : "v"(lo), "v"(hi));
    return r;
}

__device__ __forceinline__ float ex2(float x) {   // 2^x
    float r;
    asm("v_exp_f32 %0, %1" : "=v"(r) : "v"(x));
    return r;
}

__device__ __forceinline__ void gload_lds16(const void* g, const void* lds) {
    __builtin_amdgcn_global_load_lds(
        (const __attribute__((address_space(1))) unsigned int*)(unsigned long long)g,
        (__attribute__((address_space(3))) unsigned int*)(unsigned int)(unsigned long long)lds,
        16, 0, 0);
}

// ---------- fused fp32 -> bf16 conversion (x, Wq, Wk, Wv in one launch) ----------
__global__ __launch_bounds__(256) void cvt_all(const float* __restrict__ x,
                                               const float* __restrict__ wq,
                                               const float* __restrict__ wk,
                                               const float* __restrict__ wv,
                                               u16* __restrict__ xb, u16* __restrict__ wqb,
                                               u16* __restrict__ wkb, u16* __restrict__ wvb) {
    int i = blockIdx.x * 256 + threadIdx.x;   // v4 index over concatenated regions
    const float* in;
    u16* out;
    if (i < 2097152)      { in = x;  out = xb; }
    else if (i < 2359296) { in = wq; out = wqb; i -= 2097152; }
    else if (i < 2621440) { in = wk; out = wkb; i -= 2359296; }
    else                  { in = wv; out = wvb; i -= 2621440; }
    float4 v = ((const float4*)in)[i];
    ((ushort4*)out)[i] = make_ushort4(f2bf(v.x), f2bf(v.y), f2bf(v.z), f2bf(v.w));
}

// ---------- merged QKV projection GEMM (m97 structure + T2 swizzle + T1 XCD swizzle) ----------
// C[m][n] = sum_k X[m][k] * W[n][k] + bias[n]
// mode 0: Q -> [bh][s][d] bf16, scaled by 0.125*log2(e)
// mode 1: K -> [bh][s][d] bf16
// mode 2: V -> V^T [bh][d][s] bf16 (transposed via LDS)
__global__ __launch_bounds__(256, 4)
void qkv_gemm_all(const u16* __restrict__ X,
                  const u16* __restrict__ Wq, const u16* __restrict__ Wk, const u16* __restrict__ Wv,
                  const float* __restrict__ bq, const float* __restrict__ bk, const float* __restrict__ bv,
                  u16* __restrict__ Qg, u16* __restrict__ Kg, u16* __restrict__ VTg) {
    __shared__ __align__(16) char smem[34816];
    char* ldsA = smem;            // [128][64] bf16 = 16 KB, chunk-swizzled
    char* ldsB = smem + 16384;    // [128][64] bf16 = 16 KB, chunk-swizzled
    u16*  ldsE = (u16*)smem;      // epilogue [128][136]

    // XCD-chunked bijective swizzle: 1536 = 8 XCDs x 192 -> consecutive logical
    // blocks (same X m-panel) land on the same XCD's L2.
    const int l = (blockIdx.x & 7) * 192 + (blockIdx.x >> 3);
    const int mode = l >> 9;
    const int bx = l & 511;
    const u16* W = (mode == 0) ? Wq : (mode == 1) ? Wk : Wv;
    const float* bias = (mode == 0) ? bq : (mode == 1) ? bk : bv;
    u16* Out = (mode == 0) ? Qg : (mode == 1) ? Kg : VTg;

    const int t = threadIdx.x;
    const int lane = t & 63, wave = t >> 6;
    const int lhi = lane >> 4, llo = lane & 15;
    const int wm = wave >> 1, wn = wave & 1;
    const int m0 = (bx >> 3) * 128;
    const int n0 = (bx & 7) * 128;

    // staging coords: linear LDS dest, pre-swizzled global source chunk
    const int srow = (t * 16) >> 7;                    // row within 32-row slab
    const int ssc = ((t * 16) >> 4) & 7;               // linear chunk
    v4f acc[4][4] = {};

    for (int k0 = 0; k0 < 1024; k0 += 64) {
        #pragma unroll
        for (int i = 0; i < 4; ++i) {
            int row = i * 32 + srow;
            int c = ssc ^ (row & 7);                   // inverse-swizzle source
            const char* wbaseA = ldsA + (i * 256 + wave * 64) * 16;
            const char* wbaseB = ldsB + (i * 256 + wave * 64) * 16;
            gload_lds16(X + (m0 + row) * 1024 + k0 + c * 8, wbaseA);
            gload_lds16(W + (n0 + row) * 1024 + k0 + c * 8, wbaseB);
        }
        __syncthreads();
        __builtin_amdgcn_s_setprio(1);
        #pragma unroll
        for (int s = 0; s < 2; ++s) {
            v8s af[4], bf[4];
            #pragma unroll
            for (int i = 0; i < 4; ++i) {
                int r = wm * 64 + i * 16 + llo;
                af[i] = *(const v8s*)(ldsA + r * 128 + (((lhi + 4 * s) ^ (r & 7)) << 4));
            }
            #pragma unroll
            for (int j = 0; j < 4; ++j) {
                int r = wn * 64 + j * 16 + llo;
                bf[j] = *(const v8s*)(ldsB + r * 128 + (((lhi + 4 * s) ^ (r & 7)) << 4));
            }
            #pragma unroll
            for (int i = 0; i < 4; ++i)
                #pragma unroll
                for (int j = 0; j < 4; ++j)
                    acc[i][j] = __builtin_amdgcn_mfma_f32_16x16x32_bf16(af[i], bf[j], acc[i][j], 0, 0, 0);
        }
        __builtin_amdgcn_s_setprio(0);
        __syncthreads();
    }

    // epilogue: bias (+scale) -> bf16 -> LDS -> coalesced global stores
    float bv_[4];
    #pragma unroll
    for (int j = 0; j < 4; ++j) bv_[j] = bias[n0 + wn * 64 + j * 16 + llo];
    const float scl = (mode == 0) ? 0.18033688011112042f : 1.0f;   // 0.125 * log2(e)

    #pragma unroll
    for (int i = 0; i < 4; ++i) {
        #pragma unroll
        for (int j = 0; j < 4; ++j) {
            #pragma unroll
            for (int r = 0; r < 4; ++r) {
                int ml = wm * 64 + i * 16 + lhi * 4 + r;
                int nl = wn * 64 + j * 16 + llo;
                float v = (acc[i][j][r] + bv_[j]) * scl;
                u16 hh = f2bf(v);
                if (mode == 2) ldsE[nl * 136 + ml] = hh;
                else           ldsE[ml * 136 + nl] = hh;
            }
        }
    }
    __syncthreads();

    const int row = t >> 1, half = t & 1;
    if (mode == 2) {
        int n = n0 + row, hh = n >> 6, dd = n & 63;
        int b = m0 >> 11, sbase = (m0 & 2047) + half * 64;
        u16* dst = Out + ((b * 16 + hh) * 64 + dd) * 2048 + sbase;
        #pragma unroll
        for (int j = 0; j < 8; ++j)
            *(v8s*)(dst + j * 8) = *(const v8s*)&ldsE[row * 136 + half * 64 + j * 8];
    } else {
        int m = m0 + row, b = m >> 11, s = m & 2047;
        int hh = (n0 + half * 64) >> 6;
        u16* dst = Out + ((b * 16 + hh) * 2048 + s) * 64;
        #pragma unroll
        for (int j = 0; j < 8; ++j)
            *(v8s*)(dst + j * 8) = *(const v8s*)&ldsE[row * 136 + half * 64 + j * 8];
    }
}

// ---------- causal flash attention ----------
// swapped QK^T + in-register softmax + double-buffered K/V + defer-max
// Q [bh][s][d] (pre-scaled by 0.125*log2e), K [bh][s][d], VT [bh][d][s] bf16
// out fp32 [b][s][H]
__global__ __launch_bounds__(256, 3)
void flash_attn(const u16* __restrict__ Qg, const u16* __restrict__ Kg,
                const u16* __restrict__ VTg, const float* __restrict__ am,
                float* __restrict__ out) {
    __shared__ __align__(16) char smem[41472];
    char* ldsK = smem;                                   // 2 x [64][64] bf16 swizzled
    char* ldsV = smem + 16384;                           // 2 x VT [64][64] bf16 swizzled
    char* ldsP = smem + 32768 + (threadIdx.x >> 6) * 2176;  // per-wave P [16 q][68 kv] u16

    const int t = threadIdx.x;
    const int lane = t & 63, wave = t >> 6;
    const int lhi = lane >> 4, llo = lane & 15;
    const int bh = blockIdx.x;
    const int qi = 31 - blockIdx.y;        // heavy tiles dispatch first (LPT)
    const int b = bh >> 4, h = bh & 15;
    const int qw = qi * 64 + wave * 16;
    const int q = qw + llo;                // this lane's q row

    // Q fragment (B-operand layout: row n=llo, k = lhi*8 + 32s)
    v8s qf[2];
    #pragma unroll
    for (int s = 0; s < 2; ++s)
        qf[s] = *(const v8s*)(Qg + (bh * 2048 + q) * 64 + lhi * 8 + 32 * s);

    const float rowpen = am[b * 2048 + q];   // >=1.0 means fully padded row

    // stage K tile and VT tile (XOR-swizzled via pre-swizzled global source)
    const int srow = (t * 16) >> 7, ssc = ((t * 16) >> 4) & 7;
    const int sc1 = ssc ^ (srow & 7), sc2 = ssc ^ ((srow + 32) & 7);
    #define STAGE(buf, kj2) do {                                                   \
        const int kv0_ = (kj2) * 64;                                               \
        const char* wbK = ldsK + (buf) * 8192 + (wave * 64) * 16;                  \
        const char* wbV = ldsV + (buf) * 8192 + (wave * 64) * 16;                  \
        gload_lds16(Kg + (bh * 2048 + kv0_ + srow) * 64 + sc1 * 8, wbK);           \
        gload_lds16(VTg + (bh * 64 + srow) * 2048 + kv0_ + sc1 * 8, wbV);          \
        gload_lds16(Kg + (bh * 2048 + kv0_ + srow + 32) * 64 + sc2 * 8, wbK + 4096); \
        gload_lds16(VTg + (bh * 64 + srow + 32) * 2048 + kv0_ + sc2 * 8, wbV + 4096); \
    } while (0)

    float mrow = -1e30f, lrow = 0.f;
    v4f o_acc[4] = {};   // O^T: d = dt*16 + lhi*4 + r, col q = llo

    STAGE(0, 0);
    __syncthreads();

    for (int kj = 0; kj <= qi; ++kj) {
        const int cur = kj & 1;
        if (kj < qi) STAGE(cur ^ 1, kj + 1);   // prefetch: in flight during compute
        const char* K = ldsK + cur * 8192;
        const char* V = ldsV + cur * 8192;
        const int kv0 = kj * 64;

        // S^T[kv][q] = K . Q^T : A = K rows (kv), B = Q rows (q)
        const int nt4 = (kj == qi) ? (wave + 1) : 4;   // skip fully-masked diag subtiles
        v4f sacc[4] = {};
        __builtin_amdgcn_s_setprio(1);
        #pragma unroll
        for (int tt = 0; tt < 4; ++tt) {
            if (tt < nt4) {
                #pragma unroll
                for (int s = 0; s < 2; ++s) {
                    int row = tt * 16 + llo;
                    int c = lhi + 4 * s;
                    v8s kb = *(const v8s*)(K + row * 128 + ((c ^ (row & 7)) << 4));
                    sacc[tt] = __builtin_amdgcn_mfma_f32_16x16x32_bf16(kb, qf[s], sacc[tt], 0, 0, 0);
                }
            }
        }
        __builtin_amdgcn_s_setprio(0);

        // causal mask on diagonal tile (covers skipped subtiles too: sacc=0 -> -1e30)
        if (kj == qi) {
            #pragma unroll
            for (int tt = 0; tt < 4; ++tt)
                #pragma unroll
                for (int r = 0; r < 4; ++r) {
                    int kvg = kv0 + tt * 16 + lhi * 4 + r;
                    if (kvg > q) sacc[tt][r] = -1e30f;
                }
        }
        if (rowpen >= 1.0f) {
            #pragma unroll
            for (int tt = 0; tt < 4; ++tt)
                #pragma unroll
                for (int r = 0; r < 4; ++r) sacc[tt][r] = -1e30f;
        }

        // in-register online softmax (scores are base-2); defer-max rescale
        float mx = fmaxf(fmaxf(sacc[0][0], sacc[0][1]), fmaxf(sacc[0][2], sacc[0][3]));
        #pragma unroll
        for (int tt = 1; tt < 4; ++tt)
            mx = fmaxf(mx, fmaxf(fmaxf(sacc[tt][0], sacc[tt][1]), fmaxf(sacc[tt][2], sacc[tt][3])));
        mx = fmaxf(mx, __shfl_xor(mx, 16));
        mx = fmaxf(mx, __shfl_xor(mx, 32));

        if (__any(mx > mrow + 8.0f)) {        // rescale only on significant max growth
            const float mn = fmaxf(mrow, mx);
            const float sc_o = ex2(mrow - mn);
            mrow = mn;
            lrow *= sc_o;
            #pragma unroll
            for (int dt = 0; dt < 4; ++dt)
                #pragma unroll
                for (int r = 0; r < 4; ++r) o_acc[dt][r] *= sc_o;
        }

        float rs = 0.f;
        #pragma unroll
        for (int tt = 0; tt < 4; ++tt) {
            float p0 = ex2(sacc[tt][0] - mrow);
            float p1 = ex2(sacc[tt][1] - mrow);
            float p2 = ex2(sacc[tt][2] - mrow);
            float p3 = ex2(sacc[tt][3] - mrow);
            rs += (p0 + p1) + (p2 + p3);
            u32 w0 = cvt_pk_bf16(p0, p1);
            u32 w1 = cvt_pk_bf16(p2, p3);
            // P[q=llo][kv = tt*16 + lhi*4 + 0..3]
            *(u64*)(ldsP + llo * 136 + tt * 32 + lhi * 8) = (u64)w0 | ((u64)w1 << 32);
        }
        rs += __shfl_xor(rs, 16);
        rs += __shfl_xor(rs, 32);
        lrow += rs;

        // PV: O^T[d][q] += V^T[d][kv] * P^T[kv][q] ; A = V^T rows (d), B = P rows (q)
        __builtin_amdgcn_s_setprio(1);
        #pragma unroll
        for (int s = 0; s < 2; ++s) {
            u64 plo = *(const u64*)(ldsP + llo * 136 + lhi * 16 + s * 64);
            u64 phi = *(const u64*)(ldsP + llo * 136 + lhi * 16 + s * 64 + 8);
            v2u tmp; tmp.x = plo; tmp.y = phi;
            v8s pb = __builtin_bit_cast(v8s, tmp);
            #pragma unroll
            for (int dt = 0; dt < 4; ++dt) {
                int vrow = dt * 16 + llo;
                v8s vb = *(const v8s*)(V + vrow * 128 + (((lhi + 4 * s) ^ (vrow & 7)) << 4));
                o_acc[dt] = __builtin_amdgcn_mfma_f32_16x16x32_bf16(vb, pb, o_acc[dt], 0, 0, 0);
            }
        }
        __builtin_amdgcn_s_setprio(0);
        __syncthreads();   // buf[cur] reads done; prefetch into buf[cur^1] drained
    }

    // epilogue: out[b][q][h*64 + d], d = dt*16 + lhi*4 + r -> float4 stores
    const float inv = 1.0f / lrow;
    float* dst = out + (size_t)(b * 2048 + q) * 1024 + h * 64 + lhi * 4;
    #pragma unroll
    for (int dt = 0; dt < 4; ++dt) {
        float4 o;
        o.x = o_acc[dt][0] * inv;
        o.y = o_acc[dt][1] * inv;
        o.z = o_acc[dt][2] * inv;
        o.w = o_acc[dt][3] * inv;
        *(float4*)(dst + dt * 16) = o;
    }
}

// ---------- launch ----------
extern "C" void kernel_launch(void* const* d_in, const int* in_sizes, int n_in,
                              void* d_out, int out_size, void* d_ws, size_t ws_size,
                              hipStream_t stream) {
    const float* x  = (const float*)d_in[0];
    const float* Wq = (const float*)d_in[1];
    const float* bq = (const float*)d_in[2];
    const float* Wk = (const float*)d_in[3];
    const float* bk = (const float*)d_in[4];
    const float* Wv = (const float*)d_in[5];
    const float* bv = (const float*)d_in[6];
    const float* amask = (const float*)d_in[7];
    float* out = (float*)d_out;

    char* ws = (char*)d_ws;
    u16* xb  = (u16*)(ws);                         // 16 MB
    u16* Wqb = (u16*)(ws + 16777216);              // 2 MB
    u16* Wkb = (u16*)(ws + 16777216 + 2097152);
    u16* Wvb = (u16*)(ws + 16777216 + 2 * 2097152);
    u16* Qg  = (u16*)(ws + 23068672);              // 16 MB
    u16* Kg  = (u16*)(ws + 39845888);              // 16 MB
    u16* VTg = (u16*)(ws + 56623104);              // 16 MB

    cvt_all<<<11264, 256, 0, stream>>>(x, Wq, Wk, Wv, xb, Wqb, Wkb, Wvb);
    qkv_gemm_all<<<1536, 256, 0, stream>>>(xb, Wqb, Wkb, Wvb, bq, bk, bv, Qg, Kg, VTg);
    flash_attn<<<dim3(64, 32), 256, 0, stream>>>(Qg, Kg, VTg, amask, out);
}

// Round 7
// 158.181 us; speedup vs baseline: 1.9900x; 1.0102x over previous
//
#include <hip/hip_runtime.h>
#include <hip/hip_bf16.h>
#include <stdint.h>

typedef short v8s __attribute__((ext_vector_type(8)));
typedef float v4f __attribute__((ext_vector_type(4)));
typedef unsigned long long u64;
typedef unsigned short u16;
typedef unsigned int u32;
typedef u64 v2u __attribute__((ext_vector_type(2)));

// ---------- helpers ----------
__device__ __forceinline__ u16 f2bf(float f) {
    unsigned u = __builtin_bit_cast(unsigned, f);
    u += 0x7FFFu + ((u >> 16) & 1u);   // RNE
    return (u16)(u >> 16);
}

__device__ __forceinline__ u32 cvt_pk_bf16(float lo, float hi) {
    u32 r;
    asm("v_cvt_pk_bf16_f32 %0, %1, %2" : "=v"(r) : "v"(lo), "v"(hi));
    return r;
}

__device__ __forceinline__ float ex2(float x) {   // 2^x
    float r;
    asm("v_exp_f32 %0, %1" : "=v"(r) : "v"(x));
    return r;
}

__device__ __forceinline__ void gload_lds16(const void* g, const void* lds) {
    __builtin_amdgcn_global_load_lds(
        (const __attribute__((address_space(1))) unsigned int*)(unsigned long long)g,
        (__attribute__((address_space(3))) unsigned int*)(unsigned int)(unsigned long long)lds,
        16, 0, 0);
}

// ---------- fused fp32 -> bf16 conversion (x, Wq, Wk, Wv in one launch) ----------
__global__ __launch_bounds__(256) void cvt_all(const float* __restrict__ x,
                                               const float* __restrict__ wq,
                                               const float* __restrict__ wk,
                                               const float* __restrict__ wv,
                                               u16* __restrict__ xb, u16* __restrict__ wqb,
                                               u16* __restrict__ wkb, u16* __restrict__ wvb) {
    int i = blockIdx.x * 256 + threadIdx.x;   // v4 index over concatenated regions
    const float* in;
    u16* out;
    if (i < 2097152)      { in = x;  out = xb; }
    else if (i < 2359296) { in = wq; out = wqb; i -= 2097152; }
    else if (i < 2621440) { in = wk; out = wkb; i -= 2359296; }
    else                  { in = wv; out = wvb; i -= 2621440; }
    float4 v = ((const float4*)in)[i];
    ((ushort4*)out)[i] = make_ushort4(f2bf(v.x), f2bf(v.y), f2bf(v.z), f2bf(v.w));
}

// ---------- merged QKV projection GEMM (m97 structure + T2 swizzle + T1 XCD swizzle) ----------
// C[m][n] = sum_k X[m][k] * W[n][k] + bias[n]
// mode 0: Q -> [bh][s][d] bf16, scaled by 0.125*log2(e)
// mode 1: K -> [bh][s][d] bf16
// mode 2: V -> V^T [bh][d][s] bf16 (transposed via LDS)
__global__ __launch_bounds__(256, 4)
void qkv_gemm_all(const u16* __restrict__ X,
                  const u16* __restrict__ Wq, const u16* __restrict__ Wk, const u16* __restrict__ Wv,
                  const float* __restrict__ bq, const float* __restrict__ bk, const float* __restrict__ bv,
                  u16* __restrict__ Qg, u16* __restrict__ Kg, u16* __restrict__ VTg) {
    __shared__ __align__(16) char smem[34816];
    char* ldsA = smem;            // [128][64] bf16 = 16 KB, chunk-swizzled
    char* ldsB = smem + 16384;    // [128][64] bf16 = 16 KB, chunk-swizzled
    u16*  ldsE = (u16*)smem;      // epilogue [128][136]

    // XCD-chunked bijective swizzle: 1536 = 8 XCDs x 192 -> consecutive logical
    // blocks (same X m-panel) land on the same XCD's L2.
    const int l = (blockIdx.x & 7) * 192 + (blockIdx.x >> 3);
    const int mode = l >> 9;
    const int bx = l & 511;
    const u16* W = (mode == 0) ? Wq : (mode == 1) ? Wk : Wv;
    const float* bias = (mode == 0) ? bq : (mode == 1) ? bk : bv;
    u16* Out = (mode == 0) ? Qg : (mode == 1) ? Kg : VTg;

    const int t = threadIdx.x;
    const int lane = t & 63, wave = t >> 6;
    const int lhi = lane >> 4, llo = lane & 15;
    const int wm = wave >> 1, wn = wave & 1;
    const int m0 = (bx >> 3) * 128;
    const int n0 = (bx & 7) * 128;

    // staging coords: linear LDS dest, pre-swizzled global source chunk
    const int srow = (t * 16) >> 7;                    // row within 32-row slab
    const int ssc = ((t * 16) >> 4) & 7;               // linear chunk
    v4f acc[4][4] = {};

    for (int k0 = 0; k0 < 1024; k0 += 64) {
        #pragma unroll
        for (int i = 0; i < 4; ++i) {
            int row = i * 32 + srow;
            int c = ssc ^ (row & 7);                   // inverse-swizzle source
            const char* wbaseA = ldsA + (i * 256 + wave * 64) * 16;
            const char* wbaseB = ldsB + (i * 256 + wave * 64) * 16;
            gload_lds16(X + (m0 + row) * 1024 + k0 + c * 8, wbaseA);
            gload_lds16(W + (n0 + row) * 1024 + k0 + c * 8, wbaseB);
        }
        __syncthreads();
        __builtin_amdgcn_s_setprio(1);
        #pragma unroll
        for (int s = 0; s < 2; ++s) {
            v8s af[4], bf[4];
            #pragma unroll
            for (int i = 0; i < 4; ++i) {
                int r = wm * 64 + i * 16 + llo;
                af[i] = *(const v8s*)(ldsA + r * 128 + (((lhi + 4 * s) ^ (r & 7)) << 4));
            }
            #pragma unroll
            for (int j = 0; j < 4; ++j) {
                int r = wn * 64 + j * 16 + llo;
                bf[j] = *(const v8s*)(ldsB + r * 128 + (((lhi + 4 * s) ^ (r & 7)) << 4));
            }
            #pragma unroll
            for (int i = 0; i < 4; ++i)
                #pragma unroll
                for (int j = 0; j < 4; ++j)
                    acc[i][j] = __builtin_amdgcn_mfma_f32_16x16x32_bf16(af[i], bf[j], acc[i][j], 0, 0, 0);
        }
        __builtin_amdgcn_s_setprio(0);
        __syncthreads();
    }

    // epilogue: bias (+scale) -> bf16 -> LDS -> coalesced global stores
    float bv_[4];
    #pragma unroll
    for (int j = 0; j < 4; ++j) bv_[j] = bias[n0 + wn * 64 + j * 16 + llo];
    const float scl = (mode == 0) ? 0.18033688011112042f : 1.0f;   // 0.125 * log2(e)

    #pragma unroll
    for (int i = 0; i < 4; ++i) {
        #pragma unroll
        for (int j = 0; j < 4; ++j) {
            #pragma unroll
            for (int r = 0; r < 4; ++r) {
                int ml = wm * 64 + i * 16 + lhi * 4 + r;
                int nl = wn * 64 + j * 16 + llo;
                float v = (acc[i][j][r] + bv_[j]) * scl;
                u16 hh = f2bf(v);
                if (mode == 2) ldsE[nl * 136 + ml] = hh;
                else           ldsE[ml * 136 + nl] = hh;
            }
        }
    }
    __syncthreads();

    const int row = t >> 1, half = t & 1;
    if (mode == 2) {
        int n = n0 + row, hh = n >> 6, dd = n & 63;
        int b = m0 >> 11, sbase = (m0 & 2047) + half * 64;
        u16* dst = Out + ((b * 16 + hh) * 64 + dd) * 2048 + sbase;
        #pragma unroll
        for (int j = 0; j < 8; ++j)
            *(v8s*)(dst + j * 8) = *(const v8s*)&ldsE[row * 136 + half * 64 + j * 8];
    } else {
        int m = m0 + row, b = m >> 11, s = m & 2047;
        int hh = (n0 + half * 64) >> 6;
        u16* dst = Out + ((b * 16 + hh) * 2048 + s) * 64;
        #pragma unroll
        for (int j = 0; j < 8; ++j)
            *(v8s*)(dst + j * 8) = *(const v8s*)&ldsE[row * 136 + half * 64 + j * 8];
    }
}

// ---------- causal flash attention ----------
// swapped QK^T + in-register softmax + double-buffered K/V
// + T13 defer-max: per-lane threshold check BEFORE any cross-lane reduce,
//   so the steady-state tile loop has no shuffle on the critical path.
// Q [bh][s][d] (pre-scaled by 0.125*log2e), K [bh][s][d], VT [bh][d][s] bf16
// out fp32 [b][s][H]
__global__ __launch_bounds__(256, 3)
void flash_attn(const u16* __restrict__ Qg, const u16* __restrict__ Kg,
                const u16* __restrict__ VTg, const float* __restrict__ am,
                float* __restrict__ out) {
    __shared__ __align__(16) char smem[41472];
    char* ldsK = smem;                                   // 2 x [64][64] bf16 swizzled
    char* ldsV = smem + 16384;                           // 2 x VT [64][64] bf16 swizzled
    char* ldsP = smem + 32768 + (threadIdx.x >> 6) * 2176;  // per-wave P [16 q][68 kv] u16

    const int t = threadIdx.x;
    const int lane = t & 63, wave = t >> 6;
    const int lhi = lane >> 4, llo = lane & 15;
    const int bh = blockIdx.x;
    const int qi = 31 - blockIdx.y;        // heavy tiles dispatch first (LPT)
    const int b = bh >> 4, h = bh & 15;
    const int qw = qi * 64 + wave * 16;
    const int q = qw + llo;                // this lane's q row

    // Q fragment (B-operand layout: row n=llo, k = lhi*8 + 32s)
    v8s qf[2];
    #pragma unroll
    for (int s = 0; s < 2; ++s)
        qf[s] = *(const v8s*)(Qg + (bh * 2048 + q) * 64 + lhi * 8 + 32 * s);

    const float rowpen = am[b * 2048 + q];   // >=1.0 means fully padded row

    // stage K tile and VT tile (XOR-swizzled via pre-swizzled global source)
    const int srow = (t * 16) >> 7, ssc = ((t * 16) >> 4) & 7;
    const int sc1 = ssc ^ (srow & 7), sc2 = ssc ^ ((srow + 32) & 7);
    #define STAGE(buf, kj2) do {                                                   \
        const int kv0_ = (kj2) * 64;                                               \
        const char* wbK = ldsK + (buf) * 8192 + (wave * 64) * 16;                  \
        const char* wbV = ldsV + (buf) * 8192 + (wave * 64) * 16;                  \
        gload_lds16(Kg + (bh * 2048 + kv0_ + srow) * 64 + sc1 * 8, wbK);           \
        gload_lds16(VTg + (bh * 64 + srow) * 2048 + kv0_ + sc1 * 8, wbV);          \
        gload_lds16(Kg + (bh * 2048 + kv0_ + srow + 32) * 64 + sc2 * 8, wbK + 4096); \
        gload_lds16(VTg + (bh * 64 + srow + 32) * 2048 + kv0_ + sc2 * 8, wbV + 4096); \
    } while (0)

    float mrow = -1e30f, lrow = 0.f;
    v4f o_acc[4] = {};   // O^T: d = dt*16 + lhi*4 + r, col q = llo

    STAGE(0, 0);
    __syncthreads();

    for (int kj = 0; kj <= qi; ++kj) {
        const int cur = kj & 1;
        if (kj < qi) STAGE(cur ^ 1, kj + 1);   // prefetch: in flight during compute
        const char* K = ldsK + cur * 8192;
        const char* V = ldsV + cur * 8192;
        const int kv0 = kj * 64;

        // S^T[kv][q] = K . Q^T : A = K rows (kv), B = Q rows (q)
        const int nt4 = (kj == qi) ? (wave + 1) : 4;   // skip fully-masked diag subtiles
        v4f sacc[4] = {};
        __builtin_amdgcn_s_setprio(1);
        #pragma unroll
        for (int tt = 0; tt < 4; ++tt) {
            if (tt < nt4) {
                #pragma unroll
                for (int s = 0; s < 2; ++s) {
                    int row = tt * 16 + llo;
                    int c = lhi + 4 * s;
                    v8s kb = *(const v8s*)(K + row * 128 + ((c ^ (row & 7)) << 4));
                    sacc[tt] = __builtin_amdgcn_mfma_f32_16x16x32_bf16(kb, qf[s], sacc[tt], 0, 0, 0);
                }
            }
        }
        __builtin_amdgcn_s_setprio(0);

        // causal mask on diagonal tile (covers skipped subtiles too: sacc=0 -> -1e30)
        if (kj == qi) {
            #pragma unroll
            for (int tt = 0; tt < 4; ++tt)
                #pragma unroll
                for (int r = 0; r < 4; ++r) {
                    int kvg = kv0 + tt * 16 + lhi * 4 + r;
                    if (kvg > q) sacc[tt][r] = -1e30f;
                }
        }
        if (rowpen >= 1.0f) {
            #pragma unroll
            for (int tt = 0; tt < 4; ++tt)
                #pragma unroll
                for (int r = 0; r < 4; ++r) sacc[tt][r] = -1e30f;
        }

        // T13 defer-max: per-lane local max, cross-lane reduce ONLY when some
        // lane's local max exceeds mrow+8 (P stays bounded by 2^8 otherwise).
        float lmx = fmaxf(fmaxf(sacc[0][0], sacc[0][1]), fmaxf(sacc[0][2], sacc[0][3]));
        #pragma unroll
        for (int tt = 1; tt < 4; ++tt)
            lmx = fmaxf(lmx, fmaxf(fmaxf(sacc[tt][0], sacc[tt][1]), fmaxf(sacc[tt][2], sacc[tt][3])));

        if (__any(lmx > mrow + 8.0f)) {       // rare after a q-tile's first kv-tile
            float mx = fmaxf(lmx, __shfl_xor(lmx, 16));
            mx = fmaxf(mx, __shfl_xor(mx, 32));
            const float mn = fmaxf(mrow, mx);
            const float sc_o = ex2(mrow - mn);
            mrow = mn;
            lrow *= sc_o;
            #pragma unroll
            for (int dt = 0; dt < 4; ++dt)
                #pragma unroll
                for (int r = 0; r < 4; ++r) o_acc[dt][r] *= sc_o;
        }

        float rs = 0.f;
        #pragma unroll
        for (int tt = 0; tt < 4; ++tt) {
            float p0 = ex2(sacc[tt][0] - mrow);
            float p1 = ex2(sacc[tt][1] - mrow);
            float p2 = ex2(sacc[tt][2] - mrow);
            float p3 = ex2(sacc[tt][3] - mrow);
            rs += (p0 + p1) + (p2 + p3);
            u32 w0 = cvt_pk_bf16(p0, p1);
            u32 w1 = cvt_pk_bf16(p2, p3);
            // P[q=llo][kv = tt*16 + lhi*4 + 0..3]
            *(u64*)(ldsP + llo * 136 + tt * 32 + lhi * 8) = (u64)w0 | ((u64)w1 << 32);
        }
        rs += __shfl_xor(rs, 16);   // off critical path: feeds lrow only,
        rs += __shfl_xor(rs, 32);   // overlaps the PV MFMAs below
        lrow += rs;

        // PV: O^T[d][q] += V^T[d][kv] * P^T[kv][q] ; A = V^T rows (d), B = P rows (q)
        __builtin_amdgcn_s_setprio(1);
        #pragma unroll
        for (int s = 0; s < 2; ++s) {
            u64 plo = *(const u64*)(ldsP + llo * 136 + lhi * 16 + s * 64);
            u64 phi = *(const u64*)(ldsP + llo * 136 + lhi * 16 + s * 64 + 8);
            v2u tmp; tmp.x = plo; tmp.y = phi;
            v8s pb = __builtin_bit_cast(v8s, tmp);
            #pragma unroll
            for (int dt = 0; dt < 4; ++dt) {
                int vrow = dt * 16 + llo;
                v8s vb = *(const v8s*)(V + vrow * 128 + (((lhi + 4 * s) ^ (vrow & 7)) << 4));
                o_acc[dt] = __builtin_amdgcn_mfma_f32_16x16x32_bf16(vb, pb, o_acc[dt], 0, 0, 0);
            }
        }
        __builtin_amdgcn_s_setprio(0);
        __syncthreads();   // buf[cur] reads done; prefetch into buf[cur^1] drained
    }

    // epilogue: out[b][q][h*64 + d], d = dt*16 + lhi*4 + r -> float4 stores
    const float inv = 1.0f / lrow;
    float* dst = out + (size_t)(b * 2048 + q) * 1024 + h * 64 + lhi * 4;
    #pragma unroll
    for (int dt = 0; dt < 4; ++dt) {
        float4 o;
        o.x = o_acc[dt][0] * inv;
        o.y = o_acc[dt][1] * inv;
        o.z = o_acc[dt][2] * inv;
        o.w = o_acc[dt][3] * inv;
        *(float4*)(dst + dt * 16) = o;
    }
}

// ---------- launch ----------
extern "C" void kernel_launch(void* const* d_in, const int* in_sizes, int n_in,
                              void* d_out, int out_size, void* d_ws, size_t ws_size,
                              hipStream_t stream) {
    const float* x  = (const float*)d_in[0];
    const float* Wq = (const float*)d_in[1];
    const float* bq = (const float*)d_in[2];
    const float* Wk = (const float*)d_in[3];
    const float* bk = (const float*)d_in[4];
    const float* Wv = (const float*)d_in[5];
    const float* bv = (const float*)d_in[6];
    const float* amask = (const float*)d_in[7];
    float* out = (float*)d_out;

    char* ws = (char*)d_ws;
    u16* xb  = (u16*)(ws);                         // 16 MB
    u16* Wqb = (u16*)(ws + 16777216);              // 2 MB
    u16* Wkb = (u16*)(ws + 16777216 + 2097152);
    u16* Wvb = (u16*)(ws + 16777216 + 2 * 2097152);
    u16* Qg  = (u16*)(ws + 23068672);              // 16 MB
    u16* Kg  = (u16*)(ws + 39845888);              // 16 MB
    u16* VTg = (u16*)(ws + 56623104);              // 16 MB

    cvt_all<<<11264, 256, 0, stream>>>(x, Wq, Wk, Wv, xb, Wqb, Wkb, Wvb);
    qkv_gemm_all<<<1536, 256, 0, stream>>>(xb, Wqb, Wkb, Wvb, bq, bk, bv, Qg, Kg, VTg);
    flash_attn<<<dim3(64, 32), 256, 0, stream>>>(Qg, Kg, VTg, amask, out);
}